// Round 2
// baseline (1583.044 us; speedup 1.0000x reference)
//
#include <hip/hip_runtime.h>
#include <cstdint>
#include <cstddef>

#define N_V   8192
#define NR    (N_V * 4)            // 32768 attention rows
#define F_INN 512
#define F_OUT 64
#define CC    4
#define KSEL  16
#define CAP   192
#define THRESH 2.5f
#define NELEM ((size_t)NR * (size_t)N_V)   // 2^28 elements
#define NV4   (NELEM / 4)                  // 2^26 float4

// ---- ws layout (all offsets 1KB-aligned) ----
// cnt  : int   [NR]            @ 0          (128 KB)
// vals : float [NR*CAP]        @ 131072     (24 MB)
// idxs : int   [NR*CAP]        @ 25296896   (24 MB)
// h    : float [N_V*F_OUT]     @ 50462720   (2 MB)
#define WS_VALS_OFF 131072
#define WS_IDXS_OFF 25296896
#define WS_H_OFF    50462720

// ---------------- Kernel 1: h = x @ W  (fp32, vector ALU) + zero counters ----
__global__ __launch_bounds__(256) void linear_kernel(const float* __restrict__ x,
                                                     const float* __restrict__ W,
                                                     float* __restrict__ h,
                                                     int* __restrict__ cnt) {
    __shared__ float sx[16 * F_INN];
    const int tid  = threadIdx.x;
    const int gid  = blockIdx.x * 256 + tid;
    if (gid < NR) cnt[gid] = 0;   // 512 blocks x 256 = 131072 threads >= NR

    const int row0 = blockIdx.x * 16;
    const float4* x4  = (const float4*)(x + (size_t)row0 * F_INN);
    float4*       sx4 = (float4*)sx;
#pragma unroll
    for (int i = 0; i < 8; ++i) sx4[i * 256 + tid] = x4[i * 256 + tid];
    __syncthreads();

    const int f  = tid & 63;
    const int rg = tid >> 6;
    float acc0 = 0.f, acc1 = 0.f, acc2 = 0.f, acc3 = 0.f;
#pragma unroll 4
    for (int k = 0; k < F_INN; ++k) {
        const float wv = W[k * F_OUT + f];
        acc0 += sx[(rg * 4 + 0) * F_INN + k] * wv;
        acc1 += sx[(rg * 4 + 1) * F_INN + k] * wv;
        acc2 += sx[(rg * 4 + 2) * F_INN + k] * wv;
        acc3 += sx[(rg * 4 + 3) * F_INN + k] * wv;
    }
    float* hp = h + (size_t)(row0 + rg * 4) * F_OUT + f;
    hp[0 * F_OUT] = acc0;
    hp[1 * F_OUT] = acc1;
    hp[2 * F_OUT] = acc2;
    hp[3 * F_OUT] = acc3;
}

// Sortable key: higher value -> bigger key; tie -> smaller index -> bigger key.
__device__ __forceinline__ unsigned long long make_key(float v, int idx) {
    unsigned u = __float_as_uint(v);
    u = (u & 0x80000000u) ? ~u : (u | 0x80000000u);
    return ((unsigned long long)u << 32) | (unsigned long long)(0xFFFFFFFFu - (unsigned)idx);
}

// ---------------- Kernel 2: streaming threshold filter ----------------
// Pure grid-stride stream over the 1.07 GB attention matrix; no barriers,
// no tail. Candidates appended to per-row compact lists via global atomics.
__global__ __launch_bounds__(256) void filter_kernel(const float4* __restrict__ att4,
                                                     int* __restrict__ cnt,
                                                     float* __restrict__ vals,
                                                     int* __restrict__ idxs) {
    const size_t stride = (size_t)gridDim.x * 256;
    for (size_t g = (size_t)blockIdx.x * 256 + threadIdx.x; g < NV4; g += stride) {
        const float4 v = att4[g];
        if (v.x > THRESH || v.y > THRESH || v.z > THRESH || v.w > THRESH) {
            const size_t e = g * 4;
            const int row = (int)(e >> 13);        // / 8192
            const int col = (int)(e & (N_V - 1));  // % 8192
            const float vv[4] = {v.x, v.y, v.z, v.w};
#pragma unroll
            for (int c = 0; c < 4; ++c) {
                if (vv[c] > THRESH) {
                    const int p = atomicAdd(&cnt[row], 1);
                    if (p < CAP) {
                        vals[row * CAP + p] = vv[c];
                        idxs[row * CAP + p] = col + c;
                    }
                }
            }
        }
    }
}

// ---------------- Kernel 3: per-row exact top-16 + softmax + gather ----------
// One wave per row, 4 rows per block. All __syncthreads are unconditional so
// mixed good/fallback waves cannot mismatch barriers.
__global__ __launch_bounds__(256) void select_kernel(const float* __restrict__ att,
                                                     const int* __restrict__ cnt,
                                                     const float* __restrict__ vals,
                                                     const int* __restrict__ idxs,
                                                     const float* __restrict__ h,
                                                     float* __restrict__ out) {
    __shared__ float s_val[4][CAP];
    __shared__ int   s_idx[4][CAP];
    __shared__ float s_selv[4][KSEL];
    __shared__ int   s_seli[4][KSEL];

    const int tid  = threadIdx.x;
    const int lane = tid & 63;
    const int w    = tid >> 6;
    const int r    = blockIdx.x * 4 + w;

    const int c = cnt[r];
    const bool good = (c >= KSEL && c <= CAP);

    if (good) {
        for (int i = lane; i < c; i += 64) {
            s_val[w][i] = vals[r * CAP + i];
            s_idx[w][i] = idxs[r * CAP + i];
        }
    }
    __syncthreads();

    if (good) {
        for (int i = lane; i < c; i += 64) {
            const float myv = s_val[w][i];
            const int   myi = s_idx[w][i];
            int rank = 0;
            for (int j = 0; j < c; ++j) {
                const float vj = s_val[w][j];
                const int   ij = s_idx[w][j];
                rank += (vj > myv) || (vj == myv && ij < myi);
            }
            if (rank < KSEL) { s_selv[w][rank] = myv; s_seli[w][rank] = myi; }
        }
    }
    __syncthreads();

    float sv[KSEL];
    int   si[KSEL];
    if (good) {
#pragma unroll
        for (int k = 0; k < KSEL; ++k) { sv[k] = s_selv[w][k]; si[k] = s_seli[w][k]; }
    } else {
        // Exact fallback (rare): 16 rounds of bounded wave-argmax over the row.
        const float* rowp = att + (size_t)r * N_V;
        unsigned long long bound = ~0ull;
        for (int round = 0; round < KSEL; ++round) {
            unsigned long long best = 0ull;
            for (int i = lane; i < N_V; i += 64) {
                const unsigned long long k = make_key(rowp[i], i);
                if (k < bound && k > best) best = k;
            }
#pragma unroll
            for (int off = 32; off > 0; off >>= 1) {
                const unsigned long long o = __shfl_down(best, off);
                if (o > best) best = o;
            }
            best = __shfl(best, 0);   // broadcast winner
            const unsigned u    = (unsigned)(best >> 32);
            const unsigned bits = (u & 0x80000000u) ? (u & 0x7FFFFFFFu) : ~u;
            sv[round] = __uint_as_float(bits);
            si[round] = (int)(0xFFFFFFFFu - (unsigned)(best & 0xFFFFFFFFu));
            bound = best;
        }
    }

    // Softmax over the 16 (rank 0 = row max), then weighted gather of h rows.
    const float m = sv[0];
    float e[KSEL];
    float ssum = 0.f;
#pragma unroll
    for (int k = 0; k < KSEL; ++k) { e[k] = expf(sv[k] - m); ssum += e[k]; }

    float acc = 0.f;
#pragma unroll
    for (int k = 0; k < KSEL; ++k) acc += e[k] * h[(size_t)si[k] * F_OUT + lane];

    const int ch = r >> 13;          // r / N_V
    const int n  = r & (N_V - 1);    // r % N_V
    out[(size_t)n * (CC * F_OUT) + ch * F_OUT + lane] = acc / ssum;
}

extern "C" void kernel_launch(void* const* d_in, const int* in_sizes, int n_in,
                              void* d_out, int out_size, void* d_ws, size_t ws_size,
                              hipStream_t stream) {
    const float* x   = (const float*)d_in[0];  // [8192, 512]
    const float* W   = (const float*)d_in[1];  // [512, 64]
    const float* att = (const float*)d_in[2];  // [32768, 8192]
    float*       out = (float*)d_out;          // [8192, 256]

    char* ws = (char*)d_ws;
    int*   cnt  = (int*)ws;
    float* vals = (float*)(ws + WS_VALS_OFF);
    int*   idxs = (int*)(ws + WS_IDXS_OFF);
    float* h    = (float*)(ws + WS_H_OFF);

    linear_kernel<<<N_V / 16, 256, 0, stream>>>(x, W, h, cnt);
    filter_kernel<<<8192, 256, 0, stream>>>((const float4*)att, cnt, vals, idxs);
    select_kernel<<<NR / 4, 256, 0, stream>>>(att, cnt, vals, idxs, h, out);
}